// Round 4
// baseline (216.604 us; speedup 1.0000x reference)
//
#include <hip/hip_runtime.h>

#define NB 16384
#define NC 1000
#define NF 256

typedef _Float16 half8 __attribute__((ext_vector_type(8)));
typedef _Float16 half4v __attribute__((ext_vector_type(4)));
typedef float f32x4 __attribute__((ext_vector_type(4)));

// ---- prep: means fp32->fp16; SoA per-class params m2 / shape / loc*isc / isc ----
__global__ __launch_bounds__(256) void prep_means_kernel(
    const float* __restrict__ mean_vecs,
    const float* __restrict__ wb_shape,
    const float* __restrict__ wb_loc,
    const float* __restrict__ wb_scale,
    _Float16* __restrict__ m16,
    float* __restrict__ pm2,
    float* __restrict__ psh,
    float* __restrict__ pli,
    float* __restrict__ pis)
{
    const int wave = threadIdx.x >> 6;
    const int lane = threadIdx.x & 63;
    const int r = blockIdx.x * 4 + wave;          // grid=250 -> classes 0..999
    const float4* src = (const float4*)(mean_vecs + (size_t)r * NF);
    float4 v = src[lane];
    half4v h;
    h[0] = (_Float16)v.x; h[1] = (_Float16)v.y;
    h[2] = (_Float16)v.z; h[3] = (_Float16)v.w;
    *(half4v*)(m16 + (size_t)r * NF + lane * 4) = h;
    float s = v.x*v.x + v.y*v.y + v.z*v.z + v.w*v.w;
    #pragma unroll
    for (int off = 1; off < 64; off <<= 1) s += __shfl_xor(s, off, 64);
    if (lane == 0) {
        float isc = 1.0f / wb_scale[r];
        pm2[r] = s;                 // ||m_c||^2 exact fp32
        psh[r] = wb_shape[r];
        pli[r] = wb_loc[r] * isc;   // loc/scale
        pis[r] = isc;
    }
}

// ---- main: fused distance-GEMM (fp16 MFMA, A=means B=features) + Weibull + softmax
// block = 512 threads = 8 waves sharing rows [row0, row0+16).
// Wave w owns classes [w*128, w*128+128). D[m=class][n=row]: lane(q,mr) holds
// classes c0+4q..+3 of batch row row0+mr -> dwordx4 logits/stores, no f2 shuffles.
__global__ __launch_bounds__(512, 3) void openmax_kernel(
    const float* __restrict__ logits,
    const float* __restrict__ features,
    const _Float16* __restrict__ m16,
    const float* __restrict__ pm2,
    const float* __restrict__ psh,
    const float* __restrict__ pli,
    const float* __restrict__ pis,
    float* __restrict__ out)
{
    __shared__ float part[16][8];         // [row][wave] partial softmax sums

    const int lane = threadIdx.x & 63;
    const int wave = threadIdx.x >> 6;
    const int q    = lane >> 4;           // 0..3  (k-quad / class sub-group)
    const int mr   = lane & 15;           // batch row within tile
    const int row0 = blockIdx.x * 16;
    const int row  = row0 + mr;
    const int cbase = wave * 128;

    // ---- B fragments (features) + exact-fp32 f2 ----
    half8 bfrag[8];
    float f2 = 0.f;
    const float* fb = features + (size_t)row * NF;
    #pragma unroll
    for (int kk = 0; kk < 8; ++kk) {
        const float4* p = (const float4*)(fb + kk * 32 + q * 8);
        float4 lo = p[0], hi = p[1];
        f2 += lo.x*lo.x + lo.y*lo.y + lo.z*lo.z + lo.w*lo.w
            + hi.x*hi.x + hi.y*hi.y + hi.z*hi.z + hi.w*hi.w;
        half8 b;
        b[0]=(_Float16)lo.x; b[1]=(_Float16)lo.y; b[2]=(_Float16)lo.z; b[3]=(_Float16)lo.w;
        b[4]=(_Float16)hi.x; b[5]=(_Float16)hi.y; b[6]=(_Float16)hi.z; b[7]=(_Float16)hi.w;
        bfrag[kk] = b;
    }

    // ---- prefetch ALL 8 tiles' logits (L3/HBM: longest latency, issue first) ----
    float4 lg4[8];
    int lcol[8];
    #pragma unroll
    for (int i = 0; i < 8; ++i) {
        int cb = cbase + i * 16 + q * 4;
        cb = (cb > 996) ? 996 : cb;       // clamp keeps 16B alignment (996%4==0)
        lcol[i] = cb;
        lg4[i] = *(const float4*)(logits + (size_t)row * NC + cb);
    }

    // f2 reduce over k-quads; every lane ends with full ||f_row||^2 of its row
    f2 += __shfl_xor(f2, 16, 64);
    f2 += __shfl_xor(f2, 32, 64);

    const float LOG2E = 1.44269504088896340736f;
    float rsum = 0.f;
    half4v eh[8];

    // ---- A fragments (means) for tile 0 ----
    half8 cur[8], nxt[8];
    {
        int cc = cbase + mr;
        cc = (cc > NC - 1) ? (NC - 1) : cc;
        const _Float16* mb = m16 + (size_t)cc * NF;
        #pragma unroll
        for (int kk = 0; kk < 8; ++kk)
            cur[kk] = *(const half8*)(mb + kk * 32 + q * 8);
    }

    #pragma unroll
    for (int i = 0; i < 8; ++i) {
        // software pipeline: issue next tile's A-frag loads before using cur
        if (i < 7) {
            int cc = cbase + (i + 1) * 16 + mr;
            cc = (cc > NC - 1) ? (NC - 1) : cc;
            const _Float16* mb = m16 + (size_t)cc * NF;
            #pragma unroll
            for (int kk = 0; kk < 8; ++kk)
                nxt[kk] = *(const half8*)(mb + kk * 32 + q * 8);
        }

        // per-class params (SoA, L1-broadcast within q-group)
        const int cb = lcol[i];
        float4 m2v = *(const float4*)(pm2 + cb);
        float4 shv = *(const float4*)(psh + cb);
        float4 liv = *(const float4*)(pli + cb);
        float4 iv  = *(const float4*)(pis + cb);

        f32x4 acc = {0.f, 0.f, 0.f, 0.f};
        #pragma unroll
        for (int kk = 0; kk < 8; ++kk)
            acc = __builtin_amdgcn_mfma_f32_16x16x32_f16(cur[kk], bfrag[kk], acc, 0, 0, 0);

        const bool cvg = (cbase + i * 16 + q * 4) <= 996;  // all-4-or-none validity
        const float4 lg = lg4[i];
        const float* m2a = (const float*)&m2v;
        const float* sha = (const float*)&shv;
        const float* lia = (const float*)&liv;
        const float* iva = (const float*)&iv;
        const float* lga = (const float*)&lg;

        #pragma unroll
        for (int j = 0; j < 4; ++j) {
            float d2   = fmaxf(f2 + m2a[j] - 2.0f * acc[j], 1e-12f);
            float dist = sqrtf(d2);
            float xp   = dist * iva[j] - lia[j];           // (dist-loc)/scale
            float xs   = fmaxf(xp, 1e-30f);
            float t    = exp2f(sha[j] * log2f(xs));        // xp^shape
            float w    = 1.0f - exp2f(-LOG2E * t);         // weibull CDF
            w = (xp > 0.f) ? w : 0.f;
            float w2 = w * w, w4 = w2 * w2, w8 = w4 * w4;
            float s  = lga[j] * (1.0f - w8 * w2);          // logit*(1-w^10)
            float e  = exp2f(LOG2E * s);                   // exp(s), |s|<~6
            e = cvg ? e : 0.f;
            rsum += e;
            eh[i][j] = (_Float16)e;
        }

        #pragma unroll
        for (int kk = 0; kk < 8; ++kk) cur[kk] = nxt[kk];
    }

    // ---- softmax sum: intra-wave over q, then cross-wave via tiny LDS ----
    rsum += __shfl_xor(rsum, 16, 64);
    rsum += __shfl_xor(rsum, 32, 64);
    if (lane < 16) part[lane][wave] = rsum;   // lane==mr, q==0
    __syncthreads();

    const float4* pp = (const float4*)part[mr];
    float4 pa = pp[0], pb = pp[1];
    const float inv = 1.0f / (pa.x + pa.y + pa.z + pa.w + pb.x + pb.y + pb.z + pb.w);

    // ---- normalize + dwordx4 stores ----
    #pragma unroll
    for (int i = 0; i < 8; ++i) {
        if ((cbase + i * 16 + q * 4) <= 996) {
            float4 o;
            o.x = (float)eh[i][0] * inv;
            o.y = (float)eh[i][1] * inv;
            o.z = (float)eh[i][2] * inv;
            o.w = (float)eh[i][3] * inv;
            *(float4*)(out + (size_t)row * NC + lcol[i]) = o;
        }
    }
}

extern "C" void kernel_launch(void* const* d_in, const int* in_sizes, int n_in,
                              void* d_out, int out_size, void* d_ws, size_t ws_size,
                              hipStream_t stream) {
    const float* logits    = (const float*)d_in[0];
    const float* features  = (const float*)d_in[1];
    const float* mean_vecs = (const float*)d_in[2];
    const float* wb_shape  = (const float*)d_in[3];
    const float* wb_loc    = (const float*)d_in[4];
    const float* wb_scale  = (const float*)d_in[5];
    float* out = (float*)d_out;

    _Float16* m16 = (_Float16*)d_ws;                     // 512000 B
    float* pm2 = (float*)((char*)d_ws + 512000);         // 4000 B each
    float* psh = (float*)((char*)d_ws + 516000);
    float* pli = (float*)((char*)d_ws + 520000);
    float* pis = (float*)((char*)d_ws + 524000);

    prep_means_kernel<<<250, 256, 0, stream>>>(mean_vecs, wb_shape, wb_loc, wb_scale,
                                               m16, pm2, psh, pli, pis);
    openmax_kernel<<<NB / 16, 512, 0, stream>>>(logits, features, m16,
                                                pm2, psh, pli, pis, out);
}

// Round 5
// 204.459 us; speedup vs baseline: 1.0594x; 1.0594x over previous
//
#include <hip/hip_runtime.h>

#define NB 16384
#define NC 1000
#define NF 256
#define LROW 1004   // padded LDS row stride (floats): even 8-per-bank b128 coverage

typedef _Float16 half8 __attribute__((ext_vector_type(8)));
typedef _Float16 half4v __attribute__((ext_vector_type(4)));
typedef float f32x4 __attribute__((ext_vector_type(4)));

// ---- prep: means fp32->fp16; SoA per-class params m2 / shape / loc*isc / isc ----
__global__ __launch_bounds__(256) void prep_means_kernel(
    const float* __restrict__ mean_vecs,
    const float* __restrict__ wb_shape,
    const float* __restrict__ wb_loc,
    const float* __restrict__ wb_scale,
    _Float16* __restrict__ m16,
    float* __restrict__ pm2,
    float* __restrict__ psh,
    float* __restrict__ pli,
    float* __restrict__ pis)
{
    const int wave = threadIdx.x >> 6;
    const int lane = threadIdx.x & 63;
    const int r = blockIdx.x * 4 + wave;          // grid=250 -> classes 0..999
    const float4* src = (const float4*)(mean_vecs + (size_t)r * NF);
    float4 v = src[lane];
    half4v h;
    h[0] = (_Float16)v.x; h[1] = (_Float16)v.y;
    h[2] = (_Float16)v.z; h[3] = (_Float16)v.w;
    *(half4v*)(m16 + (size_t)r * NF + lane * 4) = h;
    float s = v.x*v.x + v.y*v.y + v.z*v.z + v.w*v.w;
    #pragma unroll
    for (int off = 1; off < 64; off <<= 1) s += __shfl_xor(s, off, 64);
    if (lane == 0) {
        float isc = 1.0f / wb_scale[r];
        pm2[r] = s;                 // ||m_c||^2 exact fp32
        psh[r] = wb_shape[r];
        pli[r] = wb_loc[r] * isc;   // loc/scale
        pis[r] = isc;
    }
}

// ---- main: fused distance-GEMM (fp16 MFMA, A=means B=features) + Weibull + softmax
// block = 512 threads = 8 waves sharing rows [row0, row0+16).
// Logits for the 16 rows staged in LDS once (64 KB contiguous in global) so the
// tile loop's logits access is a ~120-cyc ds_read_b128 instead of ~900-cyc L3.
// Wave w owns classes [w*128, w*128+128); lane(q,mr): classes cb..cb+3, row mr.
__global__ __launch_bounds__(512, 4) void openmax_kernel(
    const float* __restrict__ logits,
    const float* __restrict__ features,
    const _Float16* __restrict__ m16,
    const float* __restrict__ pm2,
    const float* __restrict__ psh,
    const float* __restrict__ pli,
    const float* __restrict__ pis,
    float* __restrict__ out)
{
    __shared__ float lgl[16 * LROW];      // 64256 B staged logits
    __shared__ float part[16][8];         // [row][wave] partial softmax sums

    const int lane = threadIdx.x & 63;
    const int wave = threadIdx.x >> 6;
    const int q    = lane >> 4;           // 0..3  (class sub-group)
    const int mr   = lane & 15;           // batch row within tile
    const int row0 = blockIdx.x * 16;
    const int row  = row0 + mr;
    const int cbase = wave * 128;

    // ---- stage logits: 32 threads per row, 250 dwordx4 chunks per row ----
    {
        const int sr = threadIdx.x >> 5;          // 0..15
        const int sc = threadIdx.x & 31;          // 0..31
        const float* grow = logits + (size_t)(row0 + sr) * NC;
        float* lrow = lgl + sr * LROW;
        #pragma unroll
        for (int i = 0; i < 8; ++i) {
            int c = i * 32 + sc;                  // 16B-chunk index
            if (c < 250) *(float4*)(lrow + c * 4) = *(const float4*)(grow + c * 4);
        }
    }

    // ---- B fragments (features) + exact-fp32 f2 ----
    half8 bfrag[8];
    float f2 = 0.f;
    const float* fb = features + (size_t)row * NF;
    #pragma unroll
    for (int kk = 0; kk < 8; ++kk) {
        const float4* p = (const float4*)(fb + kk * 32 + q * 8);
        float4 lo = p[0], hi = p[1];
        f2 += lo.x*lo.x + lo.y*lo.y + lo.z*lo.z + lo.w*lo.w
            + hi.x*hi.x + hi.y*hi.y + hi.z*hi.z + hi.w*hi.w;
        half8 b;
        b[0]=(_Float16)lo.x; b[1]=(_Float16)lo.y; b[2]=(_Float16)lo.z; b[3]=(_Float16)lo.w;
        b[4]=(_Float16)hi.x; b[5]=(_Float16)hi.y; b[6]=(_Float16)hi.z; b[7]=(_Float16)hi.w;
        bfrag[kk] = b;
    }
    f2 += __shfl_xor(f2, 16, 64);
    f2 += __shfl_xor(f2, 32, 64);

    __syncthreads();                      // logits staged

    const float LOG2E = 1.44269504088896340736f;
    float rsum = 0.f;
    half4v eh[8];

    #pragma unroll
    for (int i = 0; i < 8; ++i) {
        int cb = cbase + i * 16 + q * 4;
        const bool cvg = (cb <= 996);     // all-4-or-none lane validity
        cb = cvg ? cb : 996;              // clamp keeps 16B alignment

        // logits from LDS (cheap); means + params from L1/L2
        const float4 lg = *(const float4*)(lgl + mr * LROW + cb);

        int cc = cbase + i * 16 + mr;
        cc = (cc > NC - 1) ? (NC - 1) : cc;
        const _Float16* mb = m16 + (size_t)cc * NF;
        half8 cur[8];
        #pragma unroll
        for (int kk = 0; kk < 8; ++kk)
            cur[kk] = *(const half8*)(mb + kk * 32 + q * 8);

        float4 m2v = *(const float4*)(pm2 + cb);
        float4 shv = *(const float4*)(psh + cb);
        float4 liv = *(const float4*)(pli + cb);
        float4 iv  = *(const float4*)(pis + cb);

        f32x4 acc = {0.f, 0.f, 0.f, 0.f};
        #pragma unroll
        for (int kk = 0; kk < 8; ++kk)
            acc = __builtin_amdgcn_mfma_f32_16x16x32_f16(cur[kk], bfrag[kk], acc, 0, 0, 0);

        const float* m2a = (const float*)&m2v;
        const float* sha = (const float*)&shv;
        const float* lia = (const float*)&liv;
        const float* iva = (const float*)&iv;
        const float* lga = (const float*)&lg;

        #pragma unroll
        for (int j = 0; j < 4; ++j) {
            float d2   = fmaxf(f2 + m2a[j] - 2.0f * acc[j], 1e-12f);
            float dist = sqrtf(d2);
            float xp   = dist * iva[j] - lia[j];           // (dist-loc)/scale
            float xs   = fmaxf(xp, 1e-30f);
            float t    = exp2f(sha[j] * log2f(xs));        // xp^shape
            float w    = 1.0f - exp2f(-LOG2E * t);         // weibull CDF
            w = (xp > 0.f) ? w : 0.f;
            float w2 = w * w, w4 = w2 * w2, w8 = w4 * w4;
            float s  = lga[j] * (1.0f - w8 * w2);          // logit*(1-w^10)
            float e  = exp2f(LOG2E * s);                   // exp(s), |s|<~6
            e = cvg ? e : 0.f;
            rsum += e;
            eh[i][j] = (_Float16)e;
        }
    }

    // ---- softmax sum: intra-wave over q, then cross-wave via tiny LDS ----
    rsum += __shfl_xor(rsum, 16, 64);
    rsum += __shfl_xor(rsum, 32, 64);
    if (lane < 16) part[lane][wave] = rsum;   // lane==mr, q==0
    __syncthreads();

    const float4* pp = (const float4*)part[mr];
    float4 pa = pp[0], pb = pp[1];
    const float inv = 1.0f / (pa.x + pa.y + pa.z + pa.w + pb.x + pb.y + pb.z + pb.w);

    // ---- normalize + dwordx4 stores ----
    #pragma unroll
    for (int i = 0; i < 8; ++i) {
        const int cb = cbase + i * 16 + q * 4;
        if (cb <= 996) {
            float4 o;
            o.x = (float)eh[i][0] * inv;
            o.y = (float)eh[i][1] * inv;
            o.z = (float)eh[i][2] * inv;
            o.w = (float)eh[i][3] * inv;
            *(float4*)(out + (size_t)row * NC + cb) = o;
        }
    }
}

extern "C" void kernel_launch(void* const* d_in, const int* in_sizes, int n_in,
                              void* d_out, int out_size, void* d_ws, size_t ws_size,
                              hipStream_t stream) {
    const float* logits    = (const float*)d_in[0];
    const float* features  = (const float*)d_in[1];
    const float* mean_vecs = (const float*)d_in[2];
    const float* wb_shape  = (const float*)d_in[3];
    const float* wb_loc    = (const float*)d_in[4];
    const float* wb_scale  = (const float*)d_in[5];
    float* out = (float*)d_out;

    _Float16* m16 = (_Float16*)d_ws;                     // 512000 B
    float* pm2 = (float*)((char*)d_ws + 512000);         // 4000 B each
    float* psh = (float*)((char*)d_ws + 516000);
    float* pli = (float*)((char*)d_ws + 520000);
    float* pis = (float*)((char*)d_ws + 524000);

    prep_means_kernel<<<250, 256, 0, stream>>>(mean_vecs, wb_shape, wb_loc, wb_scale,
                                               m16, pm2, psh, pli, pis);
    openmax_kernel<<<NB / 16, 512, 0, stream>>>(logits, features, m16,
                                                pm2, psh, pli, pis, out);
}

// Round 6
// 192.467 us; speedup vs baseline: 1.1254x; 1.0623x over previous
//
#include <hip/hip_runtime.h>

#define NB 16384
#define NC 1000
#define NF 256
#define NT 16          // class-tiles per block (4 class-groups x 16 tiles x 16 = 1024 slots)

typedef _Float16 half8 __attribute__((ext_vector_type(8)));
typedef _Float16 half4v __attribute__((ext_vector_type(4)));
typedef float f32x4 __attribute__((ext_vector_type(4)));

typedef const __attribute__((address_space(1))) unsigned int guint;
typedef __attribute__((address_space(3))) unsigned int luint;

// ---- prep: means fp32->fp16; SoA per-class params m2 / shape / loc*isc / isc ----
__global__ __launch_bounds__(256) void prep_means_kernel(
    const float* __restrict__ mean_vecs,
    const float* __restrict__ wb_shape,
    const float* __restrict__ wb_loc,
    const float* __restrict__ wb_scale,
    _Float16* __restrict__ m16,
    float* __restrict__ pm2,
    float* __restrict__ psh,
    float* __restrict__ pli,
    float* __restrict__ pis)
{
    const int wave = threadIdx.x >> 6;
    const int lane = threadIdx.x & 63;
    const int r = blockIdx.x * 4 + wave;          // grid=250 -> classes 0..999
    const float4* src = (const float4*)(mean_vecs + (size_t)r * NF);
    float4 v = src[lane];
    half4v h;
    h[0] = (_Float16)v.x; h[1] = (_Float16)v.y;
    h[2] = (_Float16)v.z; h[3] = (_Float16)v.w;
    *(half4v*)(m16 + (size_t)r * NF + lane * 4) = h;
    float s = v.x*v.x + v.y*v.y + v.z*v.z + v.w*v.w;
    #pragma unroll
    for (int off = 1; off < 64; off <<= 1) s += __shfl_xor(s, off, 64);
    if (lane == 0) {
        float isc = 1.0f / wb_scale[r];
        pm2[r] = s;                 // ||m_c||^2 exact fp32
        psh[r] = wb_shape[r];
        pli[r] = wb_loc[r] * isc;   // loc/scale
        pis[r] = isc;
    }
}

// Stage one 16-class means tile (8 KB) into LDS, chunk-major [cchunk 0..31][class 0..15],
// via async global->LDS DMA. Each of the 8 waves issues ONE 16B-wide instruction.
__device__ __forceinline__ void stage_tile(const _Float16* __restrict__ m16,
                                           _Float16* sbuf, int c0, int wave, int lane)
{
    const int r = lane & 15;                 // class within tile
    const int cchunk = wave * 4 + (lane >> 4);   // 16B chunk of the 512B class row
    int grow = c0 + r;
    grow = (grow > NC - 1) ? (NC - 1) : grow;    // clamp tail (never read OOB)
    const _Float16* gp = m16 + (size_t)grow * NF + cchunk * 8;
    _Float16* lp = sbuf + wave * 512;        // wave-uniform base; HW adds lane*16B
    __builtin_amdgcn_global_load_lds((guint*)gp, (luint*)lp, 16, 0, 0);
}

// ---- pass 1: distance-GEMM (fp16 MFMA) + Weibull + unnormalized exp ----
// grid = 128 row-groups x 4 class-groups. Block = 8 waves x 16 rows = 128 rows,
// covering 256 classes (16 tiles). Means staged in LDS (dbuf, async DMA), shared
// by all 8 waves -> 8x less L2 means traffic. Writes e (unnormalized) to out and
// per-row partial sums to partial[cg][row]; norm_kernel rescales.
__global__ __launch_bounds__(512, 4) void score_kernel(
    const float* __restrict__ logits,
    const float* __restrict__ features,
    const _Float16* __restrict__ m16,
    const float* __restrict__ pm2,
    const float* __restrict__ psh,
    const float* __restrict__ pli,
    const float* __restrict__ pis,
    float* __restrict__ out,
    float* __restrict__ partial)
{
    __shared__ _Float16 sm[2][16 * 256];     // 2 x 8192 B means tiles

    const int lane = threadIdx.x & 63;
    const int wave = threadIdx.x >> 6;
    const int q    = lane >> 4;              // class sub-group (4 classes)
    const int mr   = lane & 15;              // row within wave's row-tile
    const int rg   = blockIdx.x >> 2;        // row-group 0..127
    const int cg   = blockIdx.x & 3;         // class-group 0..3
    const int row0w = rg * 128 + wave * 16;
    const int row   = row0w + mr;
    const int c0base = cg * 256;

    // ---- B fragments (features, this wave's 16 rows) + exact-fp32 f2 ----
    half8 bfrag[8];
    float f2 = 0.f;
    const float* fb = features + (size_t)row * NF;
    #pragma unroll
    for (int kk = 0; kk < 8; ++kk) {
        const float4* p = (const float4*)(fb + kk * 32 + q * 8);
        float4 lo = p[0], hi = p[1];
        f2 += lo.x*lo.x + lo.y*lo.y + lo.z*lo.z + lo.w*lo.w
            + hi.x*hi.x + hi.y*hi.y + hi.z*hi.z + hi.w*hi.w;
        half8 b;
        b[0]=(_Float16)lo.x; b[1]=(_Float16)lo.y; b[2]=(_Float16)lo.z; b[3]=(_Float16)lo.w;
        b[4]=(_Float16)hi.x; b[5]=(_Float16)hi.y; b[6]=(_Float16)hi.z; b[7]=(_Float16)hi.w;
        bfrag[kk] = b;
    }
    f2 += __shfl_xor(f2, 16, 64);
    f2 += __shfl_xor(f2, 32, 64);

    const float LOG2E = 1.44269504088896340736f;
    float rsum = 0.f;

    stage_tile(m16, &sm[0][0], c0base, wave, lane);   // tile 0 -> buf 0

    #pragma unroll
    for (int t = 0; t < NT; ++t) {
        __syncthreads();                     // drains DMA: buf[t&1] ready; buf[(t+1)&1] free
        if (t + 1 < NT)
            stage_tile(m16, &sm[(t + 1) & 1][0], c0base + (t + 1) * 16, wave, lane);

        const int cb  = c0base + t * 16 + q * 4;
        const bool cvg = (cb <= 996);        // all-4-or-none lane validity
        const int cbc = cvg ? cb : 996;      // clamped, keeps 16B alignment

        // logits + params straight from global (L1/L2/L3)
        const float4 lg  = *(const float4*)(logits + (size_t)row * NC + cbc);
        const float4 m2v = *(const float4*)(pm2 + cbc);
        const float4 shv = *(const float4*)(psh + cbc);
        const float4 liv = *(const float4*)(pli + cbc);
        const float4 iv  = *(const float4*)(pis + cbc);

        // A fragments (means) from LDS: static offsets, conflict-free banks
        const char* sb = (const char*)&sm[t & 1][0] + q * 256 + mr * 16;
        half8 cur[8];
        #pragma unroll
        for (int kk = 0; kk < 8; ++kk)
            cur[kk] = *(const half8*)(sb + kk * 1024);

        f32x4 acc = {0.f, 0.f, 0.f, 0.f};
        #pragma unroll
        for (int kk = 0; kk < 8; ++kk)
            acc = __builtin_amdgcn_mfma_f32_16x16x32_f16(cur[kk], bfrag[kk], acc, 0, 0, 0);

        const float* m2a = (const float*)&m2v;
        const float* sha = (const float*)&shv;
        const float* lia = (const float*)&liv;
        const float* iva = (const float*)&iv;
        const float* lga = (const float*)&lg;

        float4 o;
        float* oa = (float*)&o;
        #pragma unroll
        for (int j = 0; j < 4; ++j) {
            float d2   = fmaxf(f2 + m2a[j] - 2.0f * acc[j], 1e-12f);
            float dist = sqrtf(d2);
            float xp   = dist * iva[j] - lia[j];           // (dist-loc)/scale
            float xs   = fmaxf(xp, 1e-30f);
            float tt   = exp2f(sha[j] * log2f(xs));        // xp^shape
            float w    = 1.0f - exp2f(-LOG2E * tt);        // weibull CDF
            w = (xp > 0.f) ? w : 0.f;
            float w2 = w * w, w4 = w2 * w2, w8 = w4 * w4;
            float s  = lga[j] * (1.0f - w8 * w2);          // logit*(1-w^10)
            float e  = exp2f(LOG2E * s);                   // exp(s), |s|<~6 safe
            e = cvg ? e : 0.f;
            rsum += e;
            oa[j] = e;
        }
        if (cvg)
            *(float4*)(out + (size_t)row * NC + cb) = o;   // unnormalized exp
    }

    // per-row partial (sum over this block's 256 classes): reduce across q-groups
    rsum += __shfl_xor(rsum, 16, 64);
    rsum += __shfl_xor(rsum, 32, 64);
    if (lane < 16)
        partial[cg * NB + row0w + lane] = rsum;
}

// ---- pass 2: out *= 1 / sum(partials) -- streaming float4 rescale ----
__global__ __launch_bounds__(256) void norm_kernel(
    float* __restrict__ out,
    const float* __restrict__ partial)
{
    const int idx = blockIdx.x * 256 + threadIdx.x;   // float4 index; grid covers exactly
    const int row = idx / 250;                        // 1000 floats = 250 float4 per row
    float s = partial[row] + partial[NB + row] + partial[2 * NB + row] + partial[3 * NB + row];
    const float inv = 1.0f / s;
    float4 v = ((const float4*)out)[idx];
    v.x *= inv; v.y *= inv; v.z *= inv; v.w *= inv;
    ((float4*)out)[idx] = v;
}

extern "C" void kernel_launch(void* const* d_in, const int* in_sizes, int n_in,
                              void* d_out, int out_size, void* d_ws, size_t ws_size,
                              hipStream_t stream) {
    const float* logits    = (const float*)d_in[0];
    const float* features  = (const float*)d_in[1];
    const float* mean_vecs = (const float*)d_in[2];
    const float* wb_shape  = (const float*)d_in[3];
    const float* wb_loc    = (const float*)d_in[4];
    const float* wb_scale  = (const float*)d_in[5];
    float* out = (float*)d_out;

    // ws layout: partial 4x16384 f32 (262144 B) | m16 512000 B | params 4x4096 B
    float* partial = (float*)d_ws;
    _Float16* m16  = (_Float16*)((char*)d_ws + 262144);
    float* pm2 = (float*)((char*)d_ws + 262144 + 512000);
    float* psh = (float*)((char*)d_ws + 262144 + 512000 + 4096);
    float* pli = (float*)((char*)d_ws + 262144 + 512000 + 8192);
    float* pis = (float*)((char*)d_ws + 262144 + 512000 + 12288);

    prep_means_kernel<<<250, 256, 0, stream>>>(mean_vecs, wb_shape, wb_loc, wb_scale,
                                               m16, pm2, psh, pli, pis);
    score_kernel<<<512, 512, 0, stream>>>(logits, features, m16,
                                          pm2, psh, pli, pis, out, partial);
    norm_kernel<<<(NB * (NC / 4)) / 256, 256, 0, stream>>>(out, partial);
}